// Round 14
// baseline (193.959 us; speedup 1.0000x reference)
//
#include <hip/hip_runtime.h>
#include <math.h>

// Canny NMS mask, bit-exact vs the validated round-5 pipeline.
// v9 = v5 compute structure (best known, 58.5us) + in-block software
// pipeline: each block runs a strip of 4 vertical 64x16 tiles; tile k+1's
// global loads (6x dwordx4 -> 24 VGPRs) are issued right after tile k's
// gray-write and consumed at tile k+1's gray-write, so HBM streaming
// overlaps P2-P4 compute continuously. x-border blocks (25%) run the v5
// masked path per tile. All arithmetic chains verbatim-validated.

#define NT 256

__device__ __forceinline__ float grayf(float r, float g, float b) {
  return __fadd_rn(__fadd_rn(__fmul_rn(0.299f, r), __fmul_rn(0.587f, g)),
                   __fmul_rn(0.114f, b));
}

// sector: f32 slope test w/ guard band; in-band -> verbatim atan2f chain
__device__ __forceinline__ int sectorf(float gxf, float gyf) {
  const float Tnf = 0.41421356237309504880f;
  const float BETAf = 1e-4f;
  const float RAD2DEG = (float)(180.0 / 3.14159265358979323846);
  float uf = (gyf < 0.0f) ? -gxf : gxf;
  float vf = fabsf(gyf);
  float au = fabsf(uf);
  float p = au * Tnf, qq = vf * Tnf;
  int sec;
  if (uf > 0.0f)      sec = (vf < p) ? 0 : (uf > qq) ? 1 : 2;
  else if (uf < 0.0f) sec = (uf > -qq) ? 2 : (vf > p) ? 3 : 0;
  else                sec = (vf > 0.0f) ? 2 : 0;
  bool slow = (fabsf(vf - p) <= p * BETAf) || (fabsf(au - qq) <= qq * BETAf);
  if (slow) {
    float ang = __fmul_rn(atan2f(gyf, gxf), RAD2DEG);
    if (ang < 0.0f) ang = __fadd_rn(ang, 180.0f);
    sec = (ang < 22.5f) ? 0 : (ang < 67.5f) ? 1
        : (ang < 112.5f) ? 2 : (ang < 157.5f) ? 3 : 0;
  }
  return sec;
}

// ---------------- border path (v5 verbatim, fully masked) ----------------
__device__ __forceinline__ void canny_tile_border(
    const float* __restrict__ base, float* __restrict__ outp,
    int bx0, int by0, float* s_gray, float* s_blur, float* s_mag,
    unsigned char* s_sec, const double* w64, int tid) {
  const size_t plane = (size_t)512 * 512;

  for (int i = tid; i < 24 * 72; i += NT) {
    int ly = i / 72, lx = i - ly * 72;
    int gy = by0 - 4 + ly, gx = bx0 - 4 + lx;
    float val = 0.0f;
    if (gy >= 0 && gy < 512 && gx >= 0 && gx < 512) {
      size_t idx = (size_t)gy * 512 + gx;
      val = grayf(base[idx], base[idx + plane], base[idx + 2 * plane]);
    }
    s_gray[i] = val;
  }
  __syncthreads();

  auto blur_run = [&](int col, int q) {
    const int y0 = q * 5;
    const int ix = bx0 - 2 + col;
    const bool colok = (ix >= 0 && ix < 512);
    float win[5][5];
#pragma unroll
    for (int r = 0; r < 4; ++r)
#pragma unroll
      for (int c = 0; c < 5; ++c)
        win[r][c] = s_gray[(y0 + r) * 72 + col + c];
#pragma unroll
    for (int y = 0; y < 5; ++y) {
      const int pin = (y + 4) % 5;
#pragma unroll
      for (int c = 0; c < 5; ++c)
        win[pin][c] = s_gray[(y0 + y + 4) * 72 + col + c];
      double acc = 0.0;
#pragma unroll
      for (int r = 0; r < 5; ++r) {
        const int ph = (y + r) % 5;
#pragma unroll
        for (int c = 0; c < 5; ++c)
          acc = __builtin_fma(w64[r * 5 + c], (double)win[ph][c], acc);
      }
      int iy = by0 - 2 + y0 + y;
      s_blur[(y0 + y) * 68 + col] =
          (colok && iy >= 0 && iy < 512) ? (float)acc : 0.0f;
    }
  };
  blur_run(tid & 63, tid >> 6);
  if (tid < 16) blur_run(64 + (tid & 3), tid >> 2);
  __syncthreads();

  auto sob_run = [&](int col, int q) {
    const int y0  = (q < 2) ? q * 5 : 10 + (q - 2) * 4;
    const int len = (q < 2) ? 5 : 4;
    const int ix = bx0 - 1 + col;
    const bool colok = (ix >= 0 && ix < 512);
    float wn[3][3];
#pragma unroll
    for (int r = 0; r < 2; ++r)
#pragma unroll
      for (int c = 0; c < 3; ++c)
        wn[r][c] = s_blur[(y0 + r) * 68 + col + c];
#pragma unroll
    for (int y = 0; y < 5; ++y) {
      if (y < len) {
        const int pin = (y + 2) % 3;
#pragma unroll
        for (int c = 0; c < 3; ++c)
          wn[pin][c] = s_blur[(y0 + y + 2) * 68 + col + c];
        const int r0 = y % 3, r1 = (y + 1) % 3, r2 = (y + 2) % 3;
        double b00 = (double)wn[r0][0], b01 = (double)wn[r0][1], b02 = (double)wn[r0][2];
        double b10 = (double)wn[r1][0],                          b12 = (double)wn[r1][2];
        double b20 = (double)wn[r2][0], b21 = (double)wn[r2][1], b22 = (double)wn[r2][2];
        float gxf = (float)(((b02 - b00) + 2.0 * (b12 - b10)) + (b22 - b20));
        float gyf = (float)(((b20 - b00) + 2.0 * (b21 - b01)) + (b22 - b02));
        int iy = by0 - 1 + y0 + y;
        float mval = 0.0f;
        if (colok && iy >= 0 && iy < 512)
          mval = __fsqrt_rn(__fadd_rn(__fmul_rn(gxf, gxf), __fmul_rn(gyf, gyf)));
        s_mag[(y0 + y) * 66 + col] = mval;
        s_sec[(y0 + y) * 66 + col] = (unsigned char)sectorf(gxf, gyf);
      }
    }
  };
  sob_run(tid & 63, tid >> 6);
  if (tid < 8) sob_run(64 + (tid & 1), tid >> 1);
  __syncthreads();

  {
    const int col = tid & 63, q = tid >> 6;
    const int y0 = q * 4;
    float mw[3][3];
#pragma unroll
    for (int r = 0; r < 2; ++r)
#pragma unroll
      for (int c = 0; c < 3; ++c)
        mw[r][c] = s_mag[(y0 + r) * 66 + col + c];
#pragma unroll
    for (int y = 0; y < 4; ++y) {
      const int pin = (y + 2) % 3;
#pragma unroll
      for (int c = 0; c < 3; ++c)
        mw[pin][c] = s_mag[(y0 + y + 2) * 66 + col + c];
      const int r0 = y % 3, r1 = (y + 1) % 3, r2 = (y + 2) % 3;
      int sec = s_sec[(y0 + y + 1) * 66 + (col + 1)];
      float m = mw[r1][1];
      bool z;
      if (sec == 0)      z = (m >= mw[r1][0]) && (m >= mw[r1][2]);
      else if (sec == 1) z = (m >= mw[r2][0]) && (m >= mw[r0][2]);
      else if (sec == 2) z = (m >= mw[r0][1]) && (m >= mw[r2][1]);
      else               z = (m >= mw[r0][0]) && (m >= mw[r2][2]);
      outp[(size_t)(by0 + y0 + y) * 512 + (bx0 + col)] = z ? 0.998f : 0.002f;
    }
  }
}

// --------------- interior strip: 4 tiles, register prefetch ---------------
__device__ __forceinline__ void strip_fast(
    const float* __restrict__ base, float* __restrict__ outp,
    int bx0, int g, float* s_gray, float* s_blur, float* s_mag,
    unsigned char* s_sec, const double* w64, int tid) {
  const size_t plane = (size_t)512 * 512;
  const int rowA = tid / 18, cA = (tid - rowA * 18) * 4;
  const bool hasB = (tid < 176);
  const int tB = tid + 256;
  const int rowB = tB / 18, cB = (tB - rowB * 18) * 4;

  float4 a0, a1, a2, b0, b1, b2;

  auto prefetch = [&](int by0) {
    {
      int gy = by0 - 4 + rowA;
      int gyc = gy < 0 ? 0 : (gy > 511 ? 511 : gy);
      size_t idx = (size_t)gyc * 512 + (bx0 - 4 + cA);
      a0 = *(const float4*)(base + idx);
      a1 = *(const float4*)(base + idx + plane);
      a2 = *(const float4*)(base + idx + 2 * plane);
    }
    if (hasB) {
      int gy = by0 - 4 + rowB;
      int gyc = gy < 0 ? 0 : (gy > 511 ? 511 : gy);
      size_t idx = (size_t)gyc * 512 + (bx0 - 4 + cB);
      b0 = *(const float4*)(base + idx);
      b1 = *(const float4*)(base + idx + plane);
      b2 = *(const float4*)(base + idx + 2 * plane);
    }
  };

  auto grayW = [&](int by0) {
    {
      int gy = by0 - 4 + rowA;
      bool ok = (gy >= 0 && gy < 512);
      float4 o;
      o.x = ok ? grayf(a0.x, a1.x, a2.x) : 0.0f;
      o.y = ok ? grayf(a0.y, a1.y, a2.y) : 0.0f;
      o.z = ok ? grayf(a0.z, a1.z, a2.z) : 0.0f;
      o.w = ok ? grayf(a0.w, a1.w, a2.w) : 0.0f;
      *(float4*)(s_gray + rowA * 72 + cA) = o;
    }
    if (hasB) {
      int gy = by0 - 4 + rowB;
      bool ok = (gy >= 0 && gy < 512);
      float4 o;
      o.x = ok ? grayf(b0.x, b1.x, b2.x) : 0.0f;
      o.y = ok ? grayf(b0.y, b1.y, b2.y) : 0.0f;
      o.z = ok ? grayf(b0.z, b1.z, b2.z) : 0.0f;
      o.w = ok ? grayf(b0.w, b1.w, b2.w) : 0.0f;
      *(float4*)(s_gray + rowB * 72 + cB) = o;
    }
  };

  prefetch(g * 64);
  for (int k = 0; k < 4; ++k) {
    const int by0 = g * 64 + k * 16;
    grayW(by0);                       // compiler waits vmcnt here
    if (k < 3) prefetch(by0 + 16);    // in flight across P2..P4
    __syncthreads();

    // P2: blur 20x68 (y-masked stores only; x always interior)
    auto blur_run = [&](int col, int q) {
      const int y0 = q * 5;
      float win[5][5];
#pragma unroll
      for (int r = 0; r < 4; ++r)
#pragma unroll
        for (int c = 0; c < 5; ++c)
          win[r][c] = s_gray[(y0 + r) * 72 + col + c];
#pragma unroll
      for (int y = 0; y < 5; ++y) {
        const int pin = (y + 4) % 5;
#pragma unroll
        for (int c = 0; c < 5; ++c)
          win[pin][c] = s_gray[(y0 + y + 4) * 72 + col + c];
        double acc = 0.0;
#pragma unroll
        for (int r = 0; r < 5; ++r) {
          const int ph = (y + r) % 5;
#pragma unroll
          for (int c = 0; c < 5; ++c)
            acc = __builtin_fma(w64[r * 5 + c], (double)win[ph][c], acc);
        }
        int iy = by0 - 2 + y0 + y;
        s_blur[(y0 + y) * 68 + col] =
            (iy >= 0 && iy < 512) ? (float)acc : 0.0f;
      }
    };
    blur_run(tid & 63, tid >> 6);
    if (tid < 16) blur_run(64 + (tid & 3), tid >> 2);
    __syncthreads();

    // P3: sobel + mag + sector 18x66 (y-masked mag only)
    auto sob_run = [&](int col, int q) {
      const int y0  = (q < 2) ? q * 5 : 10 + (q - 2) * 4;
      const int len = (q < 2) ? 5 : 4;
      float wn[3][3];
#pragma unroll
      for (int r = 0; r < 2; ++r)
#pragma unroll
        for (int c = 0; c < 3; ++c)
          wn[r][c] = s_blur[(y0 + r) * 68 + col + c];
#pragma unroll
      for (int y = 0; y < 5; ++y) {
        if (y < len) {
          const int pin = (y + 2) % 3;
#pragma unroll
          for (int c = 0; c < 3; ++c)
            wn[pin][c] = s_blur[(y0 + y + 2) * 68 + col + c];
          const int r0 = y % 3, r1 = (y + 1) % 3, r2 = (y + 2) % 3;
          double b00 = (double)wn[r0][0], b01 = (double)wn[r0][1], b02 = (double)wn[r0][2];
          double b10 = (double)wn[r1][0],                          b12 = (double)wn[r1][2];
          double b20 = (double)wn[r2][0], b21 = (double)wn[r2][1], b22 = (double)wn[r2][2];
          float gxf = (float)(((b02 - b00) + 2.0 * (b12 - b10)) + (b22 - b20));
          float gyf = (float)(((b20 - b00) + 2.0 * (b21 - b01)) + (b22 - b02));
          int iy = by0 - 1 + y0 + y;
          float mval = 0.0f;
          if (iy >= 0 && iy < 512)
            mval = __fsqrt_rn(__fadd_rn(__fmul_rn(gxf, gxf), __fmul_rn(gyf, gyf)));
          s_mag[(y0 + y) * 66 + col] = mval;
          s_sec[(y0 + y) * 66 + col] = (unsigned char)sectorf(gxf, gyf);
        }
      }
    };
    sob_run(tid & 63, tid >> 6);
    if (tid < 8) sob_run(64 + (tid & 1), tid >> 1);
    __syncthreads();

    // P4: NMS 16x64
    {
      const int col = tid & 63, q = tid >> 6;
      const int y0 = q * 4;
      float mw[3][3];
#pragma unroll
      for (int r = 0; r < 2; ++r)
#pragma unroll
        for (int c = 0; c < 3; ++c)
          mw[r][c] = s_mag[(y0 + r) * 66 + col + c];
#pragma unroll
      for (int y = 0; y < 4; ++y) {
        const int pin = (y + 2) % 3;
#pragma unroll
        for (int c = 0; c < 3; ++c)
          mw[pin][c] = s_mag[(y0 + y + 2) * 66 + col + c];
        const int r0 = y % 3, r1 = (y + 1) % 3, r2 = (y + 2) % 3;
        int sec = s_sec[(y0 + y + 1) * 66 + (col + 1)];
        float m = mw[r1][1];
        bool z;
        if (sec == 0)      z = (m >= mw[r1][0]) && (m >= mw[r1][2]);
        else if (sec == 1) z = (m >= mw[r2][0]) && (m >= mw[r0][2]);
        else if (sec == 2) z = (m >= mw[r0][1]) && (m >= mw[r2][1]);
        else               z = (m >= mw[r0][0]) && (m >= mw[r2][2]);
        outp[(size_t)(by0 + y0 + y) * 512 + (bx0 + col)] = z ? 0.998f : 0.002f;
      }
    }
    if (k < 3) __syncthreads();  // s_mag overlay lives in s_gray region
  }
}

__global__ __launch_bounds__(NT, 6) void canny_v9(const float* __restrict__ x,
                                                  float* __restrict__ out) {
  __shared__ __align__(16) float s_u[1728];     // gray 24x72 / mag+sec overlay
  __shared__ __align__(16) float s_blur[1360];  // blur 20x68
  float* s_gray = s_u;
  float* s_mag  = s_u;
  unsigned char* s_sec = (unsigned char*)(s_u + 1188);

  const int tid = threadIdx.x;
  const int bid = blockIdx.x;
  const int txi = bid & 7;
  const int g   = (bid >> 3) & 7;   // strip index: 4 tiles of 16 rows
  const int n   = bid >> 6;
  const int bx0 = txi * 64;
  const float* base = x + (size_t)n * 3 * 512 * 512;
  float* outp = out + (size_t)n * 512 * 512;

  // weights: CR f32 exps, numpy-pairwise f32 sum, f32 divide (verbatim;
  // constant-folds at compile time)
  const float E05 = (float)exp(-0.5);
  const float E1  = (float)exp(-1.0);
  const float E2  = (float)exp(-2.0);
  const float E25 = (float)exp(-2.5);
  const float E4  = (float)exp(-4.0);
  const float a25[25] = {E4,E25,E2,E25,E4,  E25,E1,E05,E1,E25,
                         E2,E05,1.0f,E05,E2, E25,E1,E05,E1,E25,
                         E4,E25,E2,E25,E4};
  float r8[8];
#pragma unroll
  for (int j = 0; j < 8; ++j)
    r8[j] = __fadd_rn(__fadd_rn(a25[j], a25[j + 8]), a25[j + 16]);
  float S32 = __fadd_rn(__fadd_rn(__fadd_rn(r8[0], r8[1]), __fadd_rn(r8[2], r8[3])),
                        __fadd_rn(__fadd_rn(r8[4], r8[5]), __fadd_rn(r8[6], r8[7])));
  S32 = __fadd_rn(S32, a25[24]);
  double w64[25];
#pragma unroll
  for (int t = 0; t < 25; ++t) w64[t] = (double)__fdiv_rn(a25[t], S32);

  if (txi == 0 || txi == 7) {
    for (int k = 0; k < 4; ++k) {
      canny_tile_border(base, outp, bx0, (g * 4 + k) * 16, s_gray, s_blur,
                        s_mag, s_sec, w64, tid);
      __syncthreads();
    }
  } else {
    strip_fast(base, outp, bx0, g, s_gray, s_blur, s_mag, s_sec, w64, tid);
  }
}

extern "C" void kernel_launch(void* const* d_in, const int* in_sizes, int n_in,
                              void* d_out, int out_size, void* d_ws, size_t ws_size,
                              hipStream_t stream) {
  const float* x = (const float*)d_in[0];
  float* out = (float*)d_out;
  hipLaunchKernelGGL(canny_v9, dim3(2048), dim3(NT), 0, stream, x, out);
}

// Round 15
// 59.976 us; speedup vs baseline: 3.2340x; 3.2340x over previous
//
#include <hip/hip_runtime.h>
#include <math.h>

// Canny NMS mask, bit-exact vs the validated round-5 pipeline.
// v10 = v5 (58.5us best known) with ONE local change: sliding windows held
// in f64 REGISTERS (convert once per LDS load: blur 25->5 cvts/px, sobel
// 9->3 cvts/px). cvt_f64_f32 is a 64-bit VALU op (~4cyc) so this removes
// ~half of phase-2/3 VALU issue. Operand values bit-identical ((double)f32
// is exact); FMA/add chain order verbatim. No structural changes (lessons
// v6/v7/v8/v9: structure changes spill or trade occupancy).

#define NT 256

__device__ __forceinline__ float grayf(float r, float g, float b) {
  return __fadd_rn(__fadd_rn(__fmul_rn(0.299f, r), __fmul_rn(0.587f, g)),
                   __fmul_rn(0.114f, b));
}

// sector: f32 slope test w/ guard band; in-band -> verbatim atan2f chain
__device__ __forceinline__ int sectorf(float gxf, float gyf) {
  const float Tnf = 0.41421356237309504880f;
  const float BETAf = 1e-4f;
  const float RAD2DEG = (float)(180.0 / 3.14159265358979323846);
  float uf = (gyf < 0.0f) ? -gxf : gxf;
  float vf = fabsf(gyf);
  float au = fabsf(uf);
  float p = au * Tnf, qq = vf * Tnf;
  int sec;
  if (uf > 0.0f)      sec = (vf < p) ? 0 : (uf > qq) ? 1 : 2;
  else if (uf < 0.0f) sec = (uf > -qq) ? 2 : (vf > p) ? 3 : 0;
  else                sec = (vf > 0.0f) ? 2 : 0;
  bool slow = (fabsf(vf - p) <= p * BETAf) || (fabsf(au - qq) <= qq * BETAf);
  if (slow) {
    float ang = __fmul_rn(atan2f(gyf, gxf), RAD2DEG);
    if (ang < 0.0f) ang = __fadd_rn(ang, 180.0f);
    sec = (ang < 22.5f) ? 0 : (ang < 67.5f) ? 1
        : (ang < 112.5f) ? 2 : (ang < 157.5f) ? 3 : 0;
  }
  return sec;
}

template <bool BORDER>
__device__ __forceinline__ void canny_tile(
    const float* __restrict__ base, float* __restrict__ outp,
    int bx0, int by0, float* s_gray, float* s_blur, float* s_mag,
    unsigned char* s_sec, const double* w64, int tid) {
  const size_t plane = (size_t)512 * 512;

  // ---- Phase 1: gray 24x72 ----
  if (BORDER) {
    for (int i = tid; i < 24 * 72; i += NT) {
      int ly = i / 72, lx = i - ly * 72;
      int gy = by0 - 4 + ly, gx = bx0 - 4 + lx;
      float val = 0.0f;
      if (gy >= 0 && gy < 512 && gx >= 0 && gx < 512) {
        size_t idx = (size_t)gy * 512 + gx;
        val = grayf(base[idx], base[idx + plane], base[idx + 2 * plane]);
      }
      s_gray[i] = val;
    }
  } else {
    for (int t = tid; t < 24 * 18; t += NT) {
      int row = t / 18, c4 = (t - row * 18) * 4;
      size_t idx = (size_t)(by0 - 4 + row) * 512 + (bx0 - 4 + c4);
      float4 r = *(const float4*)(base + idx);
      float4 g = *(const float4*)(base + idx + plane);
      float4 b = *(const float4*)(base + idx + 2 * plane);
      float4 o;
      o.x = grayf(r.x, g.x, b.x);
      o.y = grayf(r.y, g.y, b.y);
      o.z = grayf(r.z, g.z, b.z);
      o.w = grayf(r.w, g.w, b.w);
      *(float4*)(s_gray + row * 72 + c4) = o;
    }
  }
  __syncthreads();

  // ---- Phase 2: blur 20x68, vertical sliding 5x5 f64-REGISTER window ----
  auto blur_run = [&](int col, int q) {
    const int y0 = q * 5;
    const int ix = bx0 - 2 + col;
    const bool colok = !BORDER || (ix >= 0 && ix < 512);
    double win[5][5];                 // cvt once per load (5/px steady state)
#pragma unroll
    for (int r = 0; r < 4; ++r)
#pragma unroll
      for (int c = 0; c < 5; ++c)
        win[r][c] = (double)s_gray[(y0 + r) * 72 + col + c];
#pragma unroll
    for (int y = 0; y < 5; ++y) {
      const int pin = (y + 4) % 5;
#pragma unroll
      for (int c = 0; c < 5; ++c)
        win[pin][c] = (double)s_gray[(y0 + y + 4) * 72 + col + c];
      double acc = 0.0;
#pragma unroll
      for (int r = 0; r < 5; ++r) {
        const int ph = (y + r) % 5;
#pragma unroll
        for (int c = 0; c < 5; ++c)
          acc = __builtin_fma(w64[r * 5 + c], win[ph][c], acc);
      }
      if (BORDER) {
        int iy = by0 - 2 + y0 + y;
        s_blur[(y0 + y) * 68 + col] =
            (colok && iy >= 0 && iy < 512) ? (float)acc : 0.0f;
      } else {
        s_blur[(y0 + y) * 68 + col] = (float)acc;
      }
    }
  };
  blur_run(tid & 63, tid >> 6);
  if (tid < 16) blur_run(64 + (tid & 3), tid >> 2);
  __syncthreads();

  // ---- Phase 3: sobel + mag + sector (18x66), f64-REGISTER 3x3 window ----
  auto sob_run = [&](int col, int q) {
    const int y0  = (q < 2) ? q * 5 : 10 + (q - 2) * 4;
    const int len = (q < 2) ? 5 : 4;
    const int ix = bx0 - 1 + col;
    const bool colok = !BORDER || (ix >= 0 && ix < 512);
    double wn[3][3];                  // cvt once per load (3/px steady state)
#pragma unroll
    for (int r = 0; r < 2; ++r)
#pragma unroll
      for (int c = 0; c < 3; ++c)
        wn[r][c] = (double)s_blur[(y0 + r) * 68 + col + c];
#pragma unroll
    for (int y = 0; y < 5; ++y) {
      if (y < len) {
        const int pin = (y + 2) % 3;
#pragma unroll
        for (int c = 0; c < 3; ++c)
          wn[pin][c] = (double)s_blur[(y0 + y + 2) * 68 + col + c];
        const int r0 = y % 3, r1 = (y + 1) % 3, r2 = (y + 2) % 3;
        double b00 = wn[r0][0], b01 = wn[r0][1], b02 = wn[r0][2];
        double b10 = wn[r1][0],                  b12 = wn[r1][2];
        double b20 = wn[r2][0], b21 = wn[r2][1], b22 = wn[r2][2];
        float gxf = (float)(((b02 - b00) + 2.0 * (b12 - b10)) + (b22 - b20));
        float gyf = (float)(((b20 - b00) + 2.0 * (b21 - b01)) + (b22 - b02));

        float mval;
        if (BORDER) {
          int iy = by0 - 1 + y0 + y;
          mval = 0.0f;
          if (colok && iy >= 0 && iy < 512)
            mval = __fsqrt_rn(__fadd_rn(__fmul_rn(gxf, gxf), __fmul_rn(gyf, gyf)));
        } else {
          mval = __fsqrt_rn(__fadd_rn(__fmul_rn(gxf, gxf), __fmul_rn(gyf, gyf)));
        }
        s_mag[(y0 + y) * 66 + col] = mval;
        s_sec[(y0 + y) * 66 + col] = (unsigned char)sectorf(gxf, gyf);
      }
    }
  };
  sob_run(tid & 63, tid >> 6);
  if (tid < 8) sob_run(64 + (tid & 1), tid >> 1);
  __syncthreads();

  // ---- Phase 4: NMS (16x64), vertical sliding 3x3 mag window ----
  {
    const int col = tid & 63, q = tid >> 6;
    const int y0 = q * 4;
    float mw[3][3];
#pragma unroll
    for (int r = 0; r < 2; ++r)
#pragma unroll
      for (int c = 0; c < 3; ++c)
        mw[r][c] = s_mag[(y0 + r) * 66 + col + c];
#pragma unroll
    for (int y = 0; y < 4; ++y) {
      const int pin = (y + 2) % 3;
#pragma unroll
      for (int c = 0; c < 3; ++c)
        mw[pin][c] = s_mag[(y0 + y + 2) * 66 + col + c];
      const int r0 = y % 3, r1 = (y + 1) % 3, r2 = (y + 2) % 3;
      int sec = s_sec[(y0 + y + 1) * 66 + (col + 1)];
      float m = mw[r1][1];
      bool z;
      if (sec == 0)      z = (m >= mw[r1][0]) && (m >= mw[r1][2]);
      else if (sec == 1) z = (m >= mw[r2][0]) && (m >= mw[r0][2]);
      else if (sec == 2) z = (m >= mw[r0][1]) && (m >= mw[r2][1]);
      else               z = (m >= mw[r0][0]) && (m >= mw[r2][2]);
      outp[(size_t)(by0 + y0 + y) * 512 + (bx0 + col)] = z ? 0.998f : 0.002f;
    }
  }
}

__global__ __launch_bounds__(NT, 6) void canny_v10(const float* __restrict__ x,
                                                   float* __restrict__ out) {
  __shared__ __align__(16) float s_u[1728];     // gray 24x72 / mag+sec overlay
  __shared__ __align__(16) float s_blur[1360];  // blur 20x68
  float* s_gray = s_u;
  float* s_mag  = s_u;
  unsigned char* s_sec = (unsigned char*)(s_u + 1188);

  const int tid = threadIdx.x;
  const int bid = blockIdx.x;
  const int txi = bid & 7, tyi = (bid >> 3) & 31;
  const int bx0 = txi * 64;
  const int by0 = tyi * 16;
  const int n   = bid >> 8;
  const float* base = x + (size_t)n * 3 * 512 * 512;
  float* outp = out + (size_t)n * 512 * 512;

  // weights: CR f32 exps, numpy-pairwise f32 sum, f32 divide (verbatim;
  // constant-folds at compile time)
  const float E05 = (float)exp(-0.5);
  const float E1  = (float)exp(-1.0);
  const float E2  = (float)exp(-2.0);
  const float E25 = (float)exp(-2.5);
  const float E4  = (float)exp(-4.0);
  const float a25[25] = {E4,E25,E2,E25,E4,  E25,E1,E05,E1,E25,
                         E2,E05,1.0f,E05,E2, E25,E1,E05,E1,E25,
                         E4,E25,E2,E25,E4};
  float r8[8];
#pragma unroll
  for (int j = 0; j < 8; ++j)
    r8[j] = __fadd_rn(__fadd_rn(a25[j], a25[j + 8]), a25[j + 16]);
  float S32 = __fadd_rn(__fadd_rn(__fadd_rn(r8[0], r8[1]), __fadd_rn(r8[2], r8[3])),
                        __fadd_rn(__fadd_rn(r8[4], r8[5]), __fadd_rn(r8[6], r8[7])));
  S32 = __fadd_rn(S32, a25[24]);
  double w64[25];
#pragma unroll
  for (int t = 0; t < 25; ++t) w64[t] = (double)__fdiv_rn(a25[t], S32);

  const bool border = (txi == 0) | (txi == 7) | (tyi == 0) | (tyi == 31);
  if (border)
    canny_tile<true>(base, outp, bx0, by0, s_gray, s_blur, s_mag, s_sec, w64, tid);
  else
    canny_tile<false>(base, outp, bx0, by0, s_gray, s_blur, s_mag, s_sec, w64, tid);
}

extern "C" void kernel_launch(void* const* d_in, const int* in_sizes, int n_in,
                              void* d_out, int out_size, void* d_ws, size_t ws_size,
                              hipStream_t stream) {
  const float* x = (const float*)d_in[0];
  float* out = (float*)d_out;
  hipLaunchKernelGGL(canny_v10, dim3(8192), dim3(NT), 0, stream, x, out);
}

// Round 17
// 58.841 us; speedup vs baseline: 3.2963x; 1.0193x over previous
//
#include <hip/hip_runtime.h>
#include <math.h>

// Canny NMS mask, bit-exact vs the validated round-5 pipeline.
// FINAL: this is v5 (round 10, 58.5us) verbatim — the best-known kernel.
// Structural attempts v6-v11 (register fusion, shfl fusion, f64 LDS,
// strip pipelining, mixed-resource phases) all regressed, stayed neutral,
// or raced; v5's phase-serial structure at the 8-block/CU wave cap is the
// practical optimum at HIP source level for this kernel shape.
//   pipeline: f32 gray (separate mul/add) -> f64-accumulated 5x5 blur
//   (row-major fma chain, one f32 rounding) -> exact-f64 sobel -> f32 mag
//   -> slope-test sector (atan2f guard band) -> f32 NMS, zero-pad borders.
// Only change vs round 10: output writes 1.0f/0.0f (absmax -> 0).

#define NT 256

__device__ __forceinline__ float grayf(float r, float g, float b) {
  return __fadd_rn(__fadd_rn(__fmul_rn(0.299f, r), __fmul_rn(0.587f, g)),
                   __fmul_rn(0.114f, b));
}

// sector: f32 slope test w/ guard band; in-band -> verbatim atan2f chain
__device__ __forceinline__ int sectorf(float gxf, float gyf) {
  const float Tnf = 0.41421356237309504880f;
  const float BETAf = 1e-4f;
  const float RAD2DEG = (float)(180.0 / 3.14159265358979323846);
  float uf = (gyf < 0.0f) ? -gxf : gxf;
  float vf = fabsf(gyf);
  float au = fabsf(uf);
  float p = au * Tnf, qq = vf * Tnf;
  int sec;
  if (uf > 0.0f)      sec = (vf < p) ? 0 : (uf > qq) ? 1 : 2;
  else if (uf < 0.0f) sec = (uf > -qq) ? 2 : (vf > p) ? 3 : 0;
  else                sec = (vf > 0.0f) ? 2 : 0;
  bool slow = (fabsf(vf - p) <= p * BETAf) || (fabsf(au - qq) <= qq * BETAf);
  if (slow) {
    float ang = __fmul_rn(atan2f(gyf, gxf), RAD2DEG);
    if (ang < 0.0f) ang = __fadd_rn(ang, 180.0f);
    sec = (ang < 22.5f) ? 0 : (ang < 67.5f) ? 1
        : (ang < 112.5f) ? 2 : (ang < 157.5f) ? 3 : 0;
  }
  return sec;
}

template <bool BORDER>
__device__ __forceinline__ void canny_tile(
    const float* __restrict__ base, float* __restrict__ outp,
    int bx0, int by0, float* s_gray, float* s_blur, float* s_mag,
    unsigned char* s_sec, const double* w64, int tid) {
  const size_t plane = (size_t)512 * 512;

  // ---- Phase 1: gray 24x72 ----
  if (BORDER) {
    for (int i = tid; i < 24 * 72; i += NT) {
      int ly = i / 72, lx = i - ly * 72;
      int gy = by0 - 4 + ly, gx = bx0 - 4 + lx;
      float val = 0.0f;
      if (gy >= 0 && gy < 512 && gx >= 0 && gx < 512) {
        size_t idx = (size_t)gy * 512 + gx;
        val = grayf(base[idx], base[idx + plane], base[idx + 2 * plane]);
      }
      s_gray[i] = val;
    }
  } else {
    for (int t = tid; t < 24 * 18; t += NT) {
      int row = t / 18, c4 = (t - row * 18) * 4;
      size_t idx = (size_t)(by0 - 4 + row) * 512 + (bx0 - 4 + c4);
      float4 r = *(const float4*)(base + idx);
      float4 g = *(const float4*)(base + idx + plane);
      float4 b = *(const float4*)(base + idx + 2 * plane);
      float4 o;
      o.x = grayf(r.x, g.x, b.x);
      o.y = grayf(r.y, g.y, b.y);
      o.z = grayf(r.z, g.z, b.z);
      o.w = grayf(r.w, g.w, b.w);
      *(float4*)(s_gray + row * 72 + c4) = o;
    }
  }
  __syncthreads();

  // ---- Phase 2: blur 20x68, vertical sliding 5x5 window, f64 fma ----
  auto blur_run = [&](int col, int q) {
    const int y0 = q * 5;
    const int ix = bx0 - 2 + col;
    const bool colok = !BORDER || (ix >= 0 && ix < 512);
    float win[5][5];
#pragma unroll
    for (int r = 0; r < 4; ++r)
#pragma unroll
      for (int c = 0; c < 5; ++c)
        win[r][c] = s_gray[(y0 + r) * 72 + col + c];
#pragma unroll
    for (int y = 0; y < 5; ++y) {
      const int pin = (y + 4) % 5;
#pragma unroll
      for (int c = 0; c < 5; ++c)
        win[pin][c] = s_gray[(y0 + y + 4) * 72 + col + c];
      double acc = 0.0;
#pragma unroll
      for (int r = 0; r < 5; ++r) {
        const int ph = (y + r) % 5;
#pragma unroll
        for (int c = 0; c < 5; ++c)
          acc = __builtin_fma(w64[r * 5 + c], (double)win[ph][c], acc);
      }
      if (BORDER) {
        int iy = by0 - 2 + y0 + y;
        s_blur[(y0 + y) * 68 + col] =
            (colok && iy >= 0 && iy < 512) ? (float)acc : 0.0f;
      } else {
        s_blur[(y0 + y) * 68 + col] = (float)acc;
      }
    }
  };
  blur_run(tid & 63, tid >> 6);
  if (tid < 16) blur_run(64 + (tid & 3), tid >> 2);
  __syncthreads();

  // ---- Phase 3: sobel + mag + sector (18x66), vertical sliding 3x3 ----
  auto sob_run = [&](int col, int q) {
    const int y0  = (q < 2) ? q * 5 : 10 + (q - 2) * 4;
    const int len = (q < 2) ? 5 : 4;
    const int ix = bx0 - 1 + col;
    const bool colok = !BORDER || (ix >= 0 && ix < 512);
    float wn[3][3];
#pragma unroll
    for (int r = 0; r < 2; ++r)
#pragma unroll
      for (int c = 0; c < 3; ++c)
        wn[r][c] = s_blur[(y0 + r) * 68 + col + c];
#pragma unroll
    for (int y = 0; y < 5; ++y) {
      if (y < len) {
        const int pin = (y + 2) % 3;
#pragma unroll
        for (int c = 0; c < 3; ++c)
          wn[pin][c] = s_blur[(y0 + y + 2) * 68 + col + c];
        const int r0 = y % 3, r1 = (y + 1) % 3, r2 = (y + 2) % 3;
        double b00 = (double)wn[r0][0], b01 = (double)wn[r0][1], b02 = (double)wn[r0][2];
        double b10 = (double)wn[r1][0],                          b12 = (double)wn[r1][2];
        double b20 = (double)wn[r2][0], b21 = (double)wn[r2][1], b22 = (double)wn[r2][2];
        float gxf = (float)(((b02 - b00) + 2.0 * (b12 - b10)) + (b22 - b20));
        float gyf = (float)(((b20 - b00) + 2.0 * (b21 - b01)) + (b22 - b02));

        float mval;
        if (BORDER) {
          int iy = by0 - 1 + y0 + y;
          mval = 0.0f;
          if (colok && iy >= 0 && iy < 512)
            mval = __fsqrt_rn(__fadd_rn(__fmul_rn(gxf, gxf), __fmul_rn(gyf, gyf)));
        } else {
          mval = __fsqrt_rn(__fadd_rn(__fmul_rn(gxf, gxf), __fmul_rn(gyf, gyf)));
        }
        s_mag[(y0 + y) * 66 + col] = mval;
        s_sec[(y0 + y) * 66 + col] = (unsigned char)sectorf(gxf, gyf);
      }
    }
  };
  sob_run(tid & 63, tid >> 6);
  if (tid < 8) sob_run(64 + (tid & 1), tid >> 1);
  __syncthreads();

  // ---- Phase 4: NMS (16x64), vertical sliding 3x3 mag window ----
  {
    const int col = tid & 63, q = tid >> 6;
    const int y0 = q * 4;
    float mw[3][3];
#pragma unroll
    for (int r = 0; r < 2; ++r)
#pragma unroll
      for (int c = 0; c < 3; ++c)
        mw[r][c] = s_mag[(y0 + r) * 66 + col + c];
#pragma unroll
    for (int y = 0; y < 4; ++y) {
      const int pin = (y + 2) % 3;
#pragma unroll
      for (int c = 0; c < 3; ++c)
        mw[pin][c] = s_mag[(y0 + y + 2) * 66 + col + c];
      const int r0 = y % 3, r1 = (y + 1) % 3, r2 = (y + 2) % 3;
      int sec = s_sec[(y0 + y + 1) * 66 + (col + 1)];
      float m = mw[r1][1];
      bool z;
      if (sec == 0)      z = (m >= mw[r1][0]) && (m >= mw[r1][2]);  // l, r
      else if (sec == 1) z = (m >= mw[r2][0]) && (m >= mw[r0][2]);  // dl, ur
      else if (sec == 2) z = (m >= mw[r0][1]) && (m >= mw[r2][1]);  // u, d
      else               z = (m >= mw[r0][0]) && (m >= mw[r2][2]);  // ul, dr
      outp[(size_t)(by0 + y0 + y) * 512 + (bx0 + col)] = z ? 1.0f : 0.0f;
    }
  }
}

__global__ __launch_bounds__(NT, 8) void canny_final(const float* __restrict__ x,
                                                     float* __restrict__ out) {
  __shared__ float s_blur[20 * 68];                     // 5440 B
  __shared__ float s_u[1728];                           // 6912 B union
  float* s_gray = s_u;                                  //   ph1-2: 24x72
  float* s_mag  = s_u;                                  //   ph3-4: 18x66
  unsigned char* s_sec = (unsigned char*)(s_u + 1188);  //   + sec bytes

  const int tid = threadIdx.x;
  const int bid = blockIdx.x;
  const int txi = bid & 7, tyi = (bid >> 3) & 31;
  const int bx0 = txi * 64;
  const int by0 = tyi * 16;
  const int n   = bid >> 8;
  const float* base = x + (size_t)n * 3 * 512 * 512;
  float* outp = out + (size_t)n * 512 * 512;

  // weights: CR f32 exps, numpy-pairwise f32 sum, f32 divide (verbatim;
  // constant-folds at compile time)
  const float E05 = (float)exp(-0.5);
  const float E1  = (float)exp(-1.0);
  const float E2  = (float)exp(-2.0);
  const float E25 = (float)exp(-2.5);
  const float E4  = (float)exp(-4.0);
  const float a25[25] = {E4,E25,E2,E25,E4,  E25,E1,E05,E1,E25,
                         E2,E05,1.0f,E05,E2, E25,E1,E05,E1,E25,
                         E4,E25,E2,E25,E4};
  float r8[8];
#pragma unroll
  for (int j = 0; j < 8; ++j)
    r8[j] = __fadd_rn(__fadd_rn(a25[j], a25[j + 8]), a25[j + 16]);
  float S32 = __fadd_rn(__fadd_rn(__fadd_rn(r8[0], r8[1]), __fadd_rn(r8[2], r8[3])),
                        __fadd_rn(__fadd_rn(r8[4], r8[5]), __fadd_rn(r8[6], r8[7])));
  S32 = __fadd_rn(S32, a25[24]);
  double w64[25];
#pragma unroll
  for (int t = 0; t < 25; ++t) w64[t] = (double)__fdiv_rn(a25[t], S32);

  const bool border = (txi == 0) | (txi == 7) | (tyi == 0) | (tyi == 31);
  if (border)
    canny_tile<true>(base, outp, bx0, by0, s_gray, s_blur, s_mag, s_sec, w64, tid);
  else
    canny_tile<false>(base, outp, bx0, by0, s_gray, s_blur, s_mag, s_sec, w64, tid);
}

extern "C" void kernel_launch(void* const* d_in, const int* in_sizes, int n_in,
                              void* d_out, int out_size, void* d_ws, size_t ws_size,
                              hipStream_t stream) {
  const float* x = (const float*)d_in[0];
  float* out = (float*)d_out;
  hipLaunchKernelGGL(canny_final, dim3(8192), dim3(NT), 0, stream, x, out);
}